// Round 8
// baseline (338.071 us; speedup 1.0000x reference)
//
#include <hip/hip_runtime.h>
#include <stdint.h>

#define B_     64
#define H_     16384
#define NB_    512
#define NNZ_   26214
#define N_IN_  1024
#define N_OUT_ 1024
#define CONVWG_ 1792                // grid-stride conv WGs (256 thr each)
#define INITWG_ 128                 // grid-stride x-init WGs

typedef __attribute__((ext_vector_type(8))) short    bf16x8;
typedef __attribute__((ext_vector_type(4))) float    f32x4;
typedef __attribute__((ext_vector_type(4))) unsigned int u32x4;

__device__ __forceinline__ unsigned short f2bf(float f) {
    union { unsigned int i; float f; } v; v.f = f;
    unsigned int x = v.i;
    return (unsigned short)((x + 0x7fffu + ((x >> 16) & 1u)) >> 16);
}

__device__ __forceinline__ bf16x8 ldfrag(const unsigned short* p) {
    union { u32x4 u; bf16x8 b; } cv;
    cv.u = *(const u32x4*)p;     // 16B aligned by construction
    return cv.b;
}

// ---------------- index build: single WG, hist+scan+scatter in LDS ----------

__global__ __launch_bounds__(1024) void index_k(
        const int* __restrict__ rows, const int* __restrict__ cols,
        int* __restrict__ rowptr, int2* __restrict__ pair2) {
    __shared__ int s_cnt[NB_];
    __shared__ int s_off[NB_];
    const int t = threadIdx.x;

    if (t < NB_) s_cnt[t] = 0;
    __syncthreads();
    for (int n = t; n < NNZ_; n += 1024)
        atomicAdd(&s_cnt[rows[n]], 1);
    __syncthreads();
    for (int off = 1; off < NB_; off <<= 1) {
        int v = 0;
        if (t < NB_ && t >= off) v = s_cnt[t - off];
        __syncthreads();
        if (t < NB_) s_cnt[t] += v;
        __syncthreads();
    }
    if (t == 0) rowptr[0] = 0;
    if (t < NB_) {
        rowptr[t + 1] = s_cnt[t];
        s_off[t] = (t == 0) ? 0 : s_cnt[t - 1];
    }
    __syncthreads();
    for (int n = t; n < NNZ_; n += 1024) {
        int r = rows[n];
        int pos = atomicAdd(&s_off[r], 1);
        pair2[pos] = make_int2(n, cols[n]);
    }
}

// ---------------- prep: grid-stride conv (f32->bf16) + blocked x init -------
// MLP fix for round-7's 66us @1.67TB/s: each thread loops over ~14 float4s
// (conv) / ~8 quads (init), keeping many loads in flight per wave instead of
// exactly one. Plain cached loads (L3-warm input helps).

__global__ __launch_bounds__(256) void prep_k(
        const float* __restrict__ w, unsigned short* __restrict__ wb,
        const float* __restrict__ inp, unsigned short* __restrict__ xb) {
    const int bb = blockIdx.x;
    if (bb < CONVWG_) {
        // flat over NNZ_*256 float4 slots (layout-preserving: wbf[n]=bf16(w[n]))
        const int total = NNZ_ * 256;
        for (int i = bb * 256 + (int)threadIdx.x; i < total; i += CONVWG_ * 256) {
            f32x4 v = ((const f32x4*)w)[i];
            union { unsigned short s[4]; uint2 d; } o;
            o.s[0] = f2bf(v[0]); o.s[1] = f2bf(v[1]);
            o.s[2] = f2bf(v[2]); o.s[3] = f2bf(v[3]);
            ((uint2*)wb)[i] = o.d;
        }
    } else {
        // blocked x[c][b][j] bf16, 4 elements (one uint2) per slot.
        // e0 = i*4 -> j = e0&31 is a multiple of 4, slab-uniform quad.
        const int total = (B_ * H_) / 4;
        for (int i = (bb - CONVWG_) * 256 + (int)threadIdx.x; i < total;
             i += INITWG_ * 256) {
            int e0 = i * 4;
            int c = e0 >> 11;
            int b = (e0 >> 5) & 63;
            int j = e0 & 31;
            int h = c * 32 + j;
            union { unsigned short s[4]; uint2 u; } o;
            if (h < N_IN_) {
                float4 vv = *(const float4*)&inp[b * N_IN_ + h];
                o.s[0] = f2bf(vv.x); o.s[1] = f2bf(vv.y);
                o.s[2] = f2bf(vv.z); o.s[3] = f2bf(vv.w);
            } else {
                o.u = make_uint2(0u, 0u);
            }
            ((uint2*)xb)[i] = o.u;
        }
    }
}

// ---------------- common pieces ---------------------------------------------

#define MFMA8(A, Bv)                                                         \
    do {                                                                     \
        _Pragma("unroll")                                                    \
        for (int mt = 0; mt < 2; ++mt)                                       \
            _Pragma("unroll")                                                \
            for (int nt = 0; nt < 4; ++nt)                                   \
                acc[mt][nt] = __builtin_amdgcn_mfma_f32_16x16x32_bf16(       \
                                  A[mt], Bv[nt], acc[mt][nt], 0, 0, 0);      \
    } while (0)

// two-phase 8->4->1 reduce + bias + activation + store epilogue.
// C/D layout: col(b within 16-tile)=lane&15, row(i)=quad*4+q.
#define REDUCE_EPILOGUE(LASTF)                                               \
    do {                                                                     \
        if (wv >= 4) {                                                       \
            _Pragma("unroll")                                                \
            for (int mt = 0; mt < 2; ++mt)                                   \
                _Pragma("unroll")                                            \
                for (int nt = 0; nt < 4; ++nt)                               \
                    _Pragma("unroll")                                        \
                    for (int q2 = 0; q2 < 4; ++q2)                           \
                        s_red[wv - 4][nt * 16 + half][mt * 16 + quad * 4 + q2] = \
                            acc[mt][nt][q2];                                 \
        }                                                                    \
        __syncthreads();                                                     \
        if (wv < 4) {                                                        \
            _Pragma("unroll")                                                \
            for (int mt = 0; mt < 2; ++mt)                                   \
                _Pragma("unroll")                                            \
                for (int nt = 0; nt < 4; ++nt)                               \
                    _Pragma("unroll")                                        \
                    for (int q2 = 0; q2 < 4; ++q2)                           \
                        s_red[wv][nt * 16 + half][mt * 16 + quad * 4 + q2] += \
                            acc[mt][nt][q2];                                 \
        }                                                                    \
        __syncthreads();                                                     \
        const int b  = tid >> 3;                                             \
        const int i0 = (tid & 7) * 4;                                        \
        const float4 bv = *(const float4*)&bias[r * 32 + i0];                \
        float v[4] = {bv.x, bv.y, bv.z, bv.w};                               \
        _Pragma("unroll")                                                    \
        for (int w = 0; w < 4; ++w)                                          \
            _Pragma("unroll")                                                \
            for (int k = 0; k < 4; ++k)                                      \
                v[k] += s_red[w][b][i0 + k];                                 \
        if (LASTF) {                                                         \
            float4 o;                                                        \
            o.x = 1.0f / (1.0f + __expf(-v[0]));                             \
            o.y = 1.0f / (1.0f + __expf(-v[1]));                             \
            o.z = 1.0f / (1.0f + __expf(-v[2]));                             \
            o.w = 1.0f / (1.0f + __expf(-v[3]));                             \
            *(float4*)&out[(size_t)b * N_OUT_ +                              \
                           (r - (NB_ - N_OUT_ / 32)) * 32 + i0] = o;         \
        } else {                                                             \
            union { unsigned short s[4]; uint2 u; } o;                       \
            _Pragma("unroll")                                                \
            for (int k = 0; k < 4; ++k)                                      \
                o.s[k] = f2bf(1.0f / (1.0f + __expf(-v[k])));                \
            *(uint2*)&xout[((size_t)r * 64 + b) * 32 + i0] = o.u;            \
        }                                                                    \
    } while (0)

// depth-2 stage load (full steps): lane j holds pair j's (weight idx, x off);
// both readlane'd with SGPR-uniform index (clamped -> redundant L1 re-hit).
#define LDST2(A, Bv, t)                                                      \
    do {                                                                     \
        int tt = ((t) < mv - 1) ? (t) : (mv - 1);                            \
        int nn = __builtin_amdgcn_readlane(nidx, tt);                        \
        const unsigned short* wp = wb + (size_t)nn * 1024 + off16;           \
        A[0] = ldfrag(wp);                                                   \
        A[1] = ldfrag(wp + 512);                                             \
        int xo = __builtin_amdgcn_readlane(xoff, tt);                        \
        const unsigned short* xp = x + xo + off16;                           \
        Bv[0] = ldfrag(xp);                                                  \
        Bv[1] = ldfrag(xp + 512);                                            \
        Bv[2] = ldfrag(xp + 1024);                                           \
        Bv[3] = ldfrag(xp + 1536);                                           \
    } while (0)

// ---------------- full step: one WG (8 waves) per row -----------------------

template <bool LAST>
__global__ __launch_bounds__(512, 4) void rowfull_k(
        const unsigned short* __restrict__ x,    // [NB][64][32] bf16 blocked
        unsigned short* __restrict__ xout,       // [NB][64][32] bf16 blocked
        float* __restrict__ out,                 // [B][N_OUT] f32 (LAST only)
        const unsigned short* __restrict__ wb,   // [NNZ][32][32] bf16 (natural)
        const float* __restrict__ bias,
        const int2* __restrict__ pair2,          // row-sorted (n, c)
        const int* __restrict__ ptr,
        int row_base) {
    __shared__ float s_red[4][64][33];           // 33.8 KB

    const int r    = blockIdx.x + row_base;
    const int tid  = threadIdx.x;
    const int wv   = tid >> 6;                   // 0..7
    const int lane = tid & 63;
    const int half = lane & 15;
    const int quad = lane >> 4;

    const int beg = ptr[r], cnt = ptr[r + 1] - beg;
    const int c0 = __builtin_amdgcn_readfirstlane(beg + (cnt * wv) / 8);
    const int mv = __builtin_amdgcn_readfirstlane(beg + (cnt * (wv + 1)) / 8 - c0);

    int nidx = 0, xoff = 0;
    if (lane < mv) {
        int2 p = pair2[c0 + lane];
        nidx = p.x;
        xoff = p.y * 2048;                       // x slab offset in shorts
    }

    const int off16 = half * 32 + quad * 8;

    f32x4 acc[2][4] = {};
    bf16x8 A0[2], B0[4], A1[2], B1[4];

    if (mv > 0) {
        LDST2(A0, B0, 0);
        LDST2(A1, B1, 1);
        int j = 0;
        while (j + 2 < mv) {
            MFMA8(A0, B0); LDST2(A0, B0, j + 2);
            MFMA8(A1, B1); LDST2(A1, B1, j + 3);
            j += 2;
        }
        MFMA8(A0, B0);
        if (mv - j > 1) MFMA8(A1, B1);
    }

    REDUCE_EPILOGUE(LAST);
}

// ---------------- step 0: column filter (c < 32), tiny work -----------------

__global__ __launch_bounds__(512, 4) void rowstep0_k(
        const unsigned short* __restrict__ x,
        unsigned short* __restrict__ xout,
        const unsigned short* __restrict__ wb,
        const float* __restrict__ bias,
        const int2* __restrict__ pair2,
        const int* __restrict__ ptr) {
    __shared__ int2  s_pairs[8][64];
    __shared__ float s_red[4][64][33];
    float* __restrict__ out = nullptr;           // unused (never LAST)

    const int r    = blockIdx.x;
    const int tid  = threadIdx.x;
    const int wv   = tid >> 6;
    const int lane = tid & 63;
    const int half = lane & 15;
    const int quad = lane >> 4;

    const int beg = ptr[r], cnt = ptr[r + 1] - beg;
    const int c0 = beg + (cnt * wv) / 8;
    const int m  = beg + (cnt * (wv + 1)) / 8 - c0;

    int2 pc = make_int2(0, 0);
    bool valid = (lane < m);
    if (valid) {
        int2 p = pair2[c0 + lane];
        pc = p;                                  // (n, c)
        valid = (p.y < N_IN_ / 32);
    }
    unsigned long long mask = __ballot(valid);
    if (valid) {
        int pos = __popcll(mask & ((1ull << lane) - 1ull));
        s_pairs[wv][pos] = pc;                   // intra-wave only: no barrier
    }
    const int mv = __popcll(mask);

    const int off16 = half * 32 + quad * 8;

    f32x4 acc[2][4] = {};
    bf16x8 A0[2], B0[4], A1[2], B1[4];

    #define LDP0(A, Bv, p)                                                   \
        do {                                                                 \
            const unsigned short* wp = wb + (size_t)(p).x * 1024 + off16;    \
            A[0] = ldfrag(wp);                                               \
            A[1] = ldfrag(wp + 512);                                         \
            const unsigned short* xp = x + (size_t)(p).y * 2048 + off16;     \
            Bv[0] = ldfrag(xp);                                              \
            Bv[1] = ldfrag(xp + 512);                                        \
            Bv[2] = ldfrag(xp + 1024);                                       \
            Bv[3] = ldfrag(xp + 1536);                                       \
        } while (0)
    if (mv > 0) { int2 p = s_pairs[wv][0]; LDP0(A0, B0, p); }
    int j = 0;
    while (j + 2 <= mv) {
        { int2 p = s_pairs[wv][j + 1]; LDP0(A1, B1, p); }
        MFMA8(A0, B0);
        if (j + 2 < mv) { int2 p = s_pairs[wv][j + 2]; LDP0(A0, B0, p); }
        MFMA8(A1, B1);
        j += 2;
    }
    if (j < mv) MFMA8(A0, B0);
    #undef LDP0

    REDUCE_EPILOGUE(false);
}

// ---------------- launcher: 10 dispatches -----------------------------------

extern "C" void kernel_launch(void* const* d_in, const int* in_sizes, int n_in,
                              void* d_out, int out_size, void* d_ws, size_t ws_size,
                              hipStream_t stream) {
    const float* inp    = (const float*)d_in[0];
    const float* blocks = (const float*)d_in[1];
    const float* bias   = (const float*)d_in[2];
    const int*   rows   = (const int*)d_in[3];
    const int*   cols   = (const int*)d_in[4];
    float*       out    = (float*)d_out;

    char* ws = (char*)d_ws;
    unsigned short* wbf = (unsigned short*)ws;                       // 53.69 MB
    unsigned short* x0  = (unsigned short*)(ws + 53686272u);         // 2 MB
    unsigned short* x1  = (unsigned short*)(ws + 53686272u + 2097152u);
    char*  idxbase      = ws + 53686272u + 2u * 2097152u;
    int*   rowptr = (int*)(idxbase);                                  // 513 ints
    int2*  pair2  = (int2*)(idxbase + 8192);                          // NNZ int2

    // 1) index build (single WG; overlaps nothing but is ~5us)
    index_k<<<1, 1024, 0, stream>>>(rows, cols, rowptr, pair2);

    // 2) grid-stride weight conversion + x init (MLP-deep, BW-bound)
    prep_k<<<CONVWG_ + INITWG_, 256, 0, stream>>>(blocks, wbf, inp, x0);

    unsigned short* cur = x0;
    unsigned short* nxt = x1;
    // 3) step 0: input nonzero only in first 32 col-blocks (filtered path)
    rowstep0_k<<<NB_, 512, 0, stream>>>(cur, nxt, wbf, bias, pair2, rowptr);
    { unsigned short* t = cur; cur = nxt; nxt = t; }
    // 4-9) steps 1..6: full rows
    for (int s = 1; s < 7; ++s) {
        rowfull_k<false><<<NB_, 512, 0, stream>>>(cur, nxt, nullptr, wbf, bias,
                                                  pair2, rowptr, 0);
        unsigned short* t = cur; cur = nxt; nxt = t;
    }
    // 10) step 7: only rows 480..511 feed the output; fused sigmoid -> f32 out
    rowfull_k<true><<<N_OUT_ / 32, 512, 0, stream>>>(cur, nullptr, out, wbf, bias,
                                                     pair2, rowptr,
                                                     NB_ - N_OUT_ / 32);
}